// Round 6
// baseline (566.763 us; speedup 1.0000x reference)
//
#include <hip/hip_runtime.h>
#include <stdint.h>

// Problem constants (fixed by setup_inputs)
constexpr int B   = 2;
constexpr int T   = 2048;
constexpr int D   = 2048;
constexpr int H   = 32;
constexpr int KVH = 8;
constexpr int HD  = 64;          // head dim
constexpr int R   = B * T;       // 4096 rows
constexpr int OKV = KVH * HD;    // 512

using bf16x8 = __attribute__((ext_vector_type(8))) __bf16;
using f32x4  = __attribute__((ext_vector_type(4))) float;
using i32x4  = __attribute__((ext_vector_type(4))) int;

__device__ inline float fast_exp2(float x) {
#if __has_builtin(__builtin_amdgcn_exp2f)
    return __builtin_amdgcn_exp2f(x);    // v_exp_f32: computes 2^x
#else
    return exp2f(x);
#endif
}

__device__ inline uint16_t f2bf(float f) {
    uint32_t u = __float_as_uint(f);
    u += 0x7fff + ((u >> 16) & 1);   // RNE
    return (uint16_t)(u >> 16);
}

// pack two f32 -> two bf16 (RNE)
__device__ inline uint32_t pack_bf16(float a, float b) {
#if __has_builtin(__builtin_amdgcn_cvt_pk_bf16_f32)
    union { __attribute__((ext_vector_type(2))) __bf16 v; uint32_t u; } r;
    r.v = __builtin_amdgcn_cvt_pk_bf16_f32(a, b);
    return r.u;
#else
    return (uint32_t)f2bf(a) | ((uint32_t)f2bf(b) << 16);
#endif
}

// async global->LDS, 16B per lane; LDS dest = (wave-uniform) base + lane*16
__device__ inline void async16(const void* g, void* l) {
    __builtin_amdgcn_global_load_lds((const __attribute__((address_space(1))) unsigned int*)g,
                                     (__attribute__((address_space(3))) unsigned int*)l,
                                     16, 0, 0);
}

// ---------------- weight scale: mean(|w|) ----------------
__global__ void absmean_kernel(const float* __restrict__ w, int n, double* __restrict__ sum) {
    __shared__ float red[256];
    int tid = threadIdx.x;
    float s = 0.f;
    for (int i = blockIdx.x * 256 + tid; i < n; i += gridDim.x * 256)
        s += fabsf(w[i]);
    red[tid] = s;
    __syncthreads();
    for (int st = 128; st > 0; st >>= 1) {
        if (tid < st) red[tid] += red[tid + st];
        __syncthreads();
    }
    if (tid == 0) atomicAdd(sum, (double)red[0]);
}

__global__ void finalize_ws_kernel(const double* __restrict__ sums, float* __restrict__ wsc,
                                   int n0, int n1, int n2, int n3) {
    int i = threadIdx.x;
    int ns[4] = {n0, n1, n2, n3};
    if (i < 4) {
        float m = (float)(sums[i] / (double)ns[i]);
        wsc[i] = fmaxf(m, 1e-5f);
    }
}

// ---------------- ternary weight quantization ----------------
__global__ void quantw_kernel(const float* __restrict__ w, int8_t* __restrict__ w8, int n,
                              const float* __restrict__ wsc, int wi) {
    float ws = wsc[wi];
    for (int i = blockIdx.x * 256 + threadIdx.x; i < n; i += gridDim.x * 256) {
        float q = rintf(w[i] / ws);
        q = fminf(fmaxf(q, -1.f), 1.f);
        w8[i] = (int8_t)q;
    }
}

// ---------------- fused rmsnorm + absmax int8 quant for q,k,v ----------------
__global__ __launch_bounds__(256) void rmsq3_kernel(const float* __restrict__ X,
        const float* __restrict__ g0, const float* __restrict__ g1, const float* __restrict__ g2,
        int8_t* __restrict__ o0, int8_t* __restrict__ o1, int8_t* __restrict__ o2,
        float* __restrict__ s0, float* __restrict__ s1, float* __restrict__ s2) {
    __shared__ float red[256];
    int row = blockIdx.x, tid = threadIdx.x;
    const float* xr = X + (size_t)row * D;
    float xv[8];
    float ss = 0.f;
#pragma unroll
    for (int i = 0; i < 8; i++) { xv[i] = xr[tid + 256 * i]; ss += xv[i] * xv[i]; }
    red[tid] = ss;
    __syncthreads();
    for (int st = 128; st > 0; st >>= 1) {
        if (tid < st) red[tid] += red[tid + st];
        __syncthreads();
    }
    float rstd = 1.0f / sqrtf(red[0] / (float)D + 1e-6f);

    const float* gs[3] = {g0, g1, g2};
    int8_t* os[3] = {o0, o1, o2};
    float* sc[3] = {s0, s1, s2};
#pragma unroll
    for (int v = 0; v < 3; v++) {
        float xn[8];
        float amax = 0.f;
#pragma unroll
        for (int i = 0; i < 8; i++) {
            xn[i] = xv[i] * rstd * gs[v][tid + 256 * i];
            amax = fmaxf(amax, fabsf(xn[i]));
        }
        __syncthreads();
        red[tid] = amax;
        __syncthreads();
        for (int st = 128; st > 0; st >>= 1) {
            if (tid < st) red[tid] = fmaxf(red[tid], red[tid + st]);
            __syncthreads();
        }
        float xsv = fmaxf(red[0], 1e-5f);
        float q127 = 127.0f / xsv;
#pragma unroll
        for (int i = 0; i < 8; i++) {
            float q = rintf(xn[i] * q127);
            q = fminf(fmaxf(q, -128.f), 127.f);
            os[v][(size_t)row * D + tid + 256 * i] = (int8_t)q;
        }
        if (tid == 0) sc[v][row] = xsv;
    }
}

// ---------------- rmsnorm + quant (single, for o-proj input) ----------------
__global__ void rmsq_kernel(const float* __restrict__ X, const float* __restrict__ g,
                            int8_t* __restrict__ Xq, float* __restrict__ xs_out) {
    __shared__ float red[256];
    int row = blockIdx.x;
    int tid = threadIdx.x;
    const float* xr = X + (size_t)row * D;

    float ss = 0.f;
    for (int i = tid; i < D; i += 256) { float v = xr[i]; ss += v * v; }
    red[tid] = ss;
    __syncthreads();
    for (int st = 128; st > 0; st >>= 1) {
        if (tid < st) red[tid] += red[tid + st];
        __syncthreads();
    }
    float ms = red[0] / (float)D;
    float rstd = 1.0f / sqrtf(ms + 1e-6f);
    __syncthreads();

    float amax = 0.f;
    for (int i = tid; i < D; i += 256) {
        float xn = xr[i] * rstd * g[i];
        amax = fmaxf(amax, fabsf(xn));
    }
    red[tid] = amax;
    __syncthreads();
    for (int st = 128; st > 0; st >>= 1) {
        if (tid < st) red[tid] = fmaxf(red[tid], red[tid + st]);
        __syncthreads();
    }
    float xs = fmaxf(red[0], 1e-5f);

    for (int i = tid; i < D; i += 256) {
        float xn = xr[i] * rstd * g[i];
        float q = rintf(xn * 127.0f / xs);
        q = fminf(fmaxf(q, -128.f), 127.f);
        Xq[(size_t)row * D + i] = (int8_t)q;
    }
    if (tid == 0) xs_out[row] = xs;
}

// ---------------- i8 MFMA GEMM ----------------
template<int BN>
__global__ __launch_bounds__(256) void gemm_i8_mfma(const int8_t* __restrict__ Xq,
                                                    const int8_t* __restrict__ W8,
                                                    float* __restrict__ out,
                                                    const float* __restrict__ xs,
                                                    const float* __restrict__ wsc, int wi,
                                                    int O) {
    constexpr int NT = BN / 32;          // n-tiles per wave
    __shared__ __align__(16) uint8_t As[128 * 128];
    __shared__ __align__(16) uint8_t Bs[BN * 128];

    const int tid  = threadIdx.x;
    const int lane = tid & 63;
    const int wv   = tid >> 6;
    const int n    = lane & 15, quad = lane >> 4;
    const int row0 = blockIdx.y * 128;
    const int col0 = blockIdx.x * BN;
    const int ws_m = (wv >> 1) * 64;
    const int ws_n = (wv & 1) * (BN / 2);

    i32x4 acc[4][NT] = {};

    for (int k0 = 0; k0 < D; k0 += 128) {
        __syncthreads();
#pragma unroll
        for (int j = 0; j < 4; j++) {
            int p = wv * 256 + j * 64 + lane;
            int r = p >> 3, s = p & 7;
            int c = s ^ (r & 7);
            async16(Xq + (size_t)(row0 + r) * D + k0 + c * 16,
                    &As[(size_t)(wv * 256 + j * 64) * 16]);
        }
#pragma unroll
        for (int j = 0; j < NT; j++) {
            int p = wv * (BN * 2) + j * 64 + lane;
            int r = p >> 3, s = p & 7;
            int c = s ^ (r & 7);
            async16(W8 + (size_t)(col0 + r) * D + k0 + c * 16,
                    &Bs[(size_t)(wv * (BN * 2) + j * 64) * 16]);
        }
        __syncthreads();
#pragma unroll
        for (int t = 0; t < 2; t++) {
            i32x4 af[4], bfr[NT];
#pragma unroll
            for (int mt = 0; mt < 4; mt++) {
                int r = ws_m + mt * 16 + n;
                af[mt] = *(const i32x4*)&As[r * 128 + (((t * 4 + quad) ^ (r & 7)) * 16)];
            }
#pragma unroll
            for (int nt = 0; nt < NT; nt++) {
                int r = ws_n + nt * 16 + n;
                bfr[nt] = *(const i32x4*)&Bs[r * 128 + (((t * 4 + quad) ^ (r & 7)) * 16)];
            }
#pragma unroll
            for (int mt = 0; mt < 4; mt++)
#pragma unroll
                for (int nt = 0; nt < NT; nt++)
                    acc[mt][nt] = __builtin_amdgcn_mfma_i32_16x16x64_i8(af[mt], bfr[nt], acc[mt][nt], 0, 0, 0);
        }
    }
    float w = wsc[wi];
#pragma unroll
    for (int mt = 0; mt < 4; mt++) {
#pragma unroll
        for (int r2 = 0; r2 < 4; r2++) {
            int row = row0 + ws_m + mt * 16 + quad * 4 + r2;
            float f = w * xs[row] * (1.0f / 127.0f);
#pragma unroll
            for (int nt = 0; nt < NT; nt++) {
                int col = col0 + ws_n + nt * 16 + n;
                out[(size_t)row * O + col] = (float)acc[mt][nt][r2] * f;
            }
        }
    }
}

// ---------------- RoPE fp32 -> bf16 ----------------
__global__ void rope_bf16_kernel(const float* __restrict__ x, const float* __restrict__ cs,
                                 const float* __restrict__ sn, uint16_t* __restrict__ o,
                                 int NH, int total) {
    int idx = blockIdx.x * 256 + threadIdx.x;
    if (idx >= total) return;
    int i = idx & 31;                 // 0..31
    int hh = (idx >> 5) % NH;
    int bt = idx / (32 * NH);         // b*T + t
    int t = bt % T;
    size_t base = ((size_t)bt * NH + hh) * HD;
    float x0 = x[base + i], x1 = x[base + i + 32];
    float c0 = cs[t * HD + i], c1 = cs[t * HD + i + 32];
    float s0 = sn[t * HD + i], s1 = sn[t * HD + i + 32];
    o[base + i]      = f2bf(x0 * c0 - x1 * s0);
    o[base + i + 32] = f2bf(x1 * c1 + x0 * s1);
}

// ---------------- V transpose: [t][kvh*64+d] f32 -> [b*KVH+kvh][d][t] bf16 --------
__global__ __launch_bounds__(256) void vtrans_kernel(const float* __restrict__ vb,
                                                     uint16_t* __restrict__ vt) {
    __shared__ float tile[64][65];
    int t0 = blockIdx.x * 64;
    int hb = blockIdx.y;              // b*KVH + kvh
    int b = hb >> 3, kvh = hb & 7;
    int tid = threadIdx.x;
    int r = tid >> 2, cg = (tid & 3) * 16;
#pragma unroll
    for (int j = 0; j < 4; j++) {
        float4 v4 = *(const float4*)(vb + (size_t)(b * T + t0 + r) * OKV + kvh * HD + cg + j * 4);
        tile[r][cg + j * 4 + 0] = v4.x;
        tile[r][cg + j * 4 + 1] = v4.y;
        tile[r][cg + j * 4 + 2] = v4.z;
        tile[r][cg + j * 4 + 3] = v4.w;
    }
    __syncthreads();
    int d = tid >> 2, tg = (tid & 3) * 16;
    uint16_t pk[16];
#pragma unroll
    for (int j = 0; j < 16; j++) pk[j] = f2bf(tile[tg + j][d]);
    *(uint4*)(vt + ((size_t)hb * 64 + d) * T + t0 + tg)     = *(uint4*)&pk[0];
    *(uint4*)(vt + ((size_t)hb * 64 + d) * T + t0 + tg + 8) = *(uint4*)&pk[8];
}

// ---------------- barrier-free MFMA flash attention ----------------
// S^T = K Q^T, O^T = V^T P^T, all K/V fragments loaded straight from global
// (L1/L2 serve reuse). grid (16, H, B); block p covers q-strips p and 31-p
// (64 q each) -> every wave does exactly 33 tile-chunk units (balanced).
__global__ __launch_bounds__(256) void attn_mfma_kernel(const uint16_t* __restrict__ qh,
                                                        const uint16_t* __restrict__ kh,
                                                        const uint16_t* __restrict__ vt,
                                                        float* __restrict__ out) {
    __shared__ __align__(16) uint16_t Pw[4][32 * 72];  // per-wave P [q][key], pad 72

    const int tid  = threadIdx.x;
    const int lane = tid & 63;
    const int wv   = tid >> 6;
    const int p = blockIdx.x, h = blockIdx.y, b = blockIdx.z;
    const int kvh = h >> 2;               // n_rep = 4
    const int n = lane & 15, quad = lane >> 4;
    const float SC = 0.125f * 1.44269504089f;   // score -> log2 units

    const int qlo[2] = { p * 64 + wv * 16, (31 - p) * 64 + wv * 16 };

    // Q B-frags: lane holds d = ks*32 + quad*8 + j, col q = n
    bf16x8 qf[2][2];
#pragma unroll
    for (int tl = 0; tl < 2; tl++) {
        const uint16_t* qp = qh + (size_t)(b * T + qlo[tl] + n) * D + h * HD + quad * 8;
        qf[tl][0] = *(const bf16x8*)(qp);
        qf[tl][1] = *(const bf16x8*)(qp + 32);
    }

    f32x4 o[2][4] = {};
    float m[2] = {-INFINITY, -INFINITY};   // raw-score domain
    float l[2] = {0.f, 0.f};

    const uint16_t* kbase = kh + (size_t)b * T * OKV + kvh * HD + (size_t)n * OKV + quad * 8;
    const uint16_t* vbase = vt + ((size_t)(b * KVH + kvh) * 64 + n) * T + quad * 8;

    const int nch = 32 - p;
    for (int ch = 0; ch < nch; ch++) {
        const int t0 = ch * 64;
        // K A-frags straight from global: row = key = t0 + mt*16 + n
        bf16x8 kf[2][4];
        const uint16_t* kc = kbase + (size_t)t0 * OKV;
#pragma unroll
        for (int ks = 0; ks < 2; ks++)
#pragma unroll
            for (int mt = 0; mt < 4; mt++)
                kf[ks][mt] = *(const bf16x8*)(kc + (size_t)mt * (16 * OKV) + ks * 32);

        const bool act0 = (ch <= p);
#pragma unroll
        for (int tl = 0; tl < 2; tl++) {
            if (tl == 0 && !act0) continue;
            f32x4 s[4] = {};
#pragma unroll
            for (int ks = 0; ks < 2; ks++)
#pragma unroll
                for (int mt = 0; mt < 4; mt++)
                    s[mt] = __builtin_amdgcn_mfma_f32_16x16x32_bf16(kf[ks][mt], qf[tl][ks], s[mt], 0, 0, 0);

            const int qg = qlo[tl] + n;
            const bool diag = (tl == 0) ? (ch == p) : (ch == nch - 1);
            float mloc = -INFINITY;
#pragma unroll
            for (int mt = 0; mt < 4; mt++) {
#pragma unroll
                for (int r2 = 0; r2 < 4; r2++) {
                    float sv = s[mt][r2];
                    if (diag) {
                        int kg = t0 + mt * 16 + quad * 4 + r2;
                        sv = (kg > qg) ? -INFINITY : sv;
                        s[mt][r2] = sv;
                    }
                    mloc = fmaxf(mloc, sv);
                }
            }
            mloc = fmaxf(mloc, __shfl_xor(mloc, 16));
            mloc = fmaxf(mloc, __shfl_xor(mloc, 32));
            float mnew = fmaxf(m[tl], mloc);
            float msc = mnew * SC;
            float corr = fast_exp2(m[tl] * SC - msc);   // first chunk: 2^-inf = 0
            float ls = 0.f;
#pragma unroll
            for (int mt = 0; mt < 4; mt++) {
                float pv[4];
#pragma unroll
                for (int r2 = 0; r2 < 4; r2++) {
                    pv[r2] = fast_exp2(__builtin_fmaf(s[mt][r2], SC, -msc));
                    ls += pv[r2];
                }
                uint32_t pk0 = pack_bf16(pv[0], pv[1]);
                uint32_t pk1 = pack_bf16(pv[2], pv[3]);
                uint2 w2; w2.x = pk0; w2.y = pk1;
                *(uint2*)&Pw[wv][(tl * 16 + n) * 72 + mt * 16 + quad * 4] = w2;
            }
            ls += __shfl_xor(ls, 16);
            ls += __shfl_xor(ls, 32);
            l[tl] = l[tl] * corr + ls;
            m[tl] = mnew;
#pragma unroll
            for (int mt = 0; mt < 4; mt++)
#pragma unroll
                for (int r2 = 0; r2 < 4; r2++) o[tl][mt][r2] *= corr;
        }

        // V^T A-frags straight from global: row = d = mt*16 + n, col = key
        bf16x8 vf[2][4];
        const uint16_t* vc = vbase + t0;
#pragma unroll
        for (int ks = 0; ks < 2; ks++)
#pragma unroll
            for (int mt = 0; mt < 4; mt++)
                vf[ks][mt] = *(const bf16x8*)(vc + (size_t)mt * (16 * T) + ks * 32);

#pragma unroll
        for (int tl = 0; tl < 2; tl++) {
            if (tl == 0 && !act0) continue;
#pragma unroll
            for (int ks = 0; ks < 2; ks++) {
                bf16x8 pf = *(const bf16x8*)&Pw[wv][(tl * 16 + n) * 72 + ks * 32 + quad * 8];
#pragma unroll
                for (int mt = 0; mt < 4; mt++)
                    o[tl][mt] = __builtin_amdgcn_mfma_f32_16x16x32_bf16(vf[ks][mt], pf, o[tl][mt], 0, 0, 0);
            }
        }
    }

#pragma unroll
    for (int tl = 0; tl < 2; tl++) {
        int qg = qlo[tl] + n;
        float inv = 1.0f / l[tl];
#pragma unroll
        for (int mt = 0; mt < 4; mt++) {
            f32x4 ov;
#pragma unroll
            for (int r2 = 0; r2 < 4; r2++) ov[r2] = o[tl][mt][r2] * inv;
            *(f32x4*)(out + (size_t)(b * T + qg) * D + h * HD + mt * 16 + quad * 4) = ov;
        }
    }
}

// ---------------- launch ----------------
extern "C" void kernel_launch(void* const* d_in, const int* in_sizes, int n_in,
                              void* d_out, int out_size, void* d_ws, size_t ws_size,
                              hipStream_t stream) {
    const float* x   = (const float*)d_in[0];
    const float* cs  = (const float*)d_in[1];
    const float* sn  = (const float*)d_in[2];
    const float* wq  = (const float*)d_in[3];
    const float* wk  = (const float*)d_in[4];
    const float* wv  = (const float*)d_in[5];
    const float* wo  = (const float*)d_in[6];
    const float* gq  = (const float*)d_in[7];
    const float* gk  = (const float*)d_in[8];
    const float* gv  = (const float*)d_in[9];
    const float* go  = (const float*)d_in[10];
    float* out = (float*)d_out;

    uint8_t* w = (uint8_t*)d_ws;
    double* wsum  = (double*)w;
    float* wscale = (float*)(w + 64);
    float* xs     = (float*)(w + 256);
    size_t off = 256 + 4 * (size_t)R * 4;
    int8_t* Wq8 = (int8_t*)(w + off); off += (size_t)D * D;
    int8_t* Wk8 = (int8_t*)(w + off); off += (size_t)OKV * D;
    int8_t* Wv8 = (int8_t*)(w + off); off += (size_t)OKV * D;
    int8_t* Wo8 = (int8_t*)(w + off); off += (size_t)D * D;
    int8_t* Xq_q = (int8_t*)(w + off); off += (size_t)R * D;
    int8_t* Xq_k = (int8_t*)(w + off); off += (size_t)R * D;
    int8_t* Xq_v = (int8_t*)(w + off); off += (size_t)R * D;
    float* qb = (float*)(w + off); off += (size_t)R * D * 4;
    float* kb = (float*)(w + off); off += (size_t)R * OKV * 4;
    float* vb = (float*)(w + off); off += (size_t)R * OKV * 4;
    uint16_t* qhb = (uint16_t*)(w + off); off += (size_t)R * D * 2;
    // overlays (regions dead by the time they're written):
    uint16_t* khb = (uint16_t*)Xq_v;   // dead after v gemm
    uint16_t* vtb = (uint16_t*)Xq_k;   // dead after k gemm; 4MB needed, 8MB region
    float*    ab  = qb;                // dead after rope q
    int8_t*   Aq8 = Xq_q;              // dead after q gemm (rewritten after attention)

    (void)hipMemsetAsync(wsum, 0, 64, stream);

    absmean_kernel<<<512, 256, 0, stream>>>(wq, D * D, wsum + 0);
    absmean_kernel<<<512, 256, 0, stream>>>(wk, OKV * D, wsum + 1);
    absmean_kernel<<<512, 256, 0, stream>>>(wv, OKV * D, wsum + 2);
    absmean_kernel<<<512, 256, 0, stream>>>(wo, D * D, wsum + 3);
    finalize_ws_kernel<<<1, 64, 0, stream>>>(wsum, wscale, D * D, OKV * D, OKV * D, D * D);

    quantw_kernel<<<4096, 256, 0, stream>>>(wq, Wq8, D * D, wscale, 0);
    quantw_kernel<<<1024, 256, 0, stream>>>(wk, Wk8, OKV * D, wscale, 1);
    quantw_kernel<<<1024, 256, 0, stream>>>(wv, Wv8, OKV * D, wscale, 2);
    quantw_kernel<<<4096, 256, 0, stream>>>(wo, Wo8, D * D, wscale, 3);

    rmsq3_kernel<<<R, 256, 0, stream>>>(x, gq, gk, gv, Xq_q, Xq_k, Xq_v,
                                        xs + 0 * R, xs + 1 * R, xs + 2 * R);

    gemm_i8_mfma<128><<<dim3(D / 128, R / 128), 256, 0, stream>>>(Xq_q, Wq8, qb, xs + 0 * R, wscale, 0, D);
    gemm_i8_mfma<64><<<dim3(OKV / 64, R / 128), 256, 0, stream>>>(Xq_k, Wk8, kb, xs + 1 * R, wscale, 1, OKV);
    gemm_i8_mfma<64><<<dim3(OKV / 64, R / 128), 256, 0, stream>>>(Xq_v, Wv8, vb, xs + 2 * R, wscale, 2, OKV);

    {
        int totq = R * H * 32;
        rope_bf16_kernel<<<(totq + 255) / 256, 256, 0, stream>>>(qb, cs, sn, qhb, H, totq);
        int totk = R * KVH * 32;
        rope_bf16_kernel<<<(totk + 255) / 256, 256, 0, stream>>>(kb, cs, sn, khb, KVH, totk);
        vtrans_kernel<<<dim3(T / 64, B * KVH), 256, 0, stream>>>(vb, vtb);
    }

    attn_mfma_kernel<<<dim3(16, H, B), 256, 0, stream>>>(qhb, khb, vtb, ab);

    rmsq_kernel<<<R, 256, 0, stream>>>(ab, go, Aq8, xs + 3 * R);
    gemm_i8_mfma<128><<<dim3(D / 128, R / 128), 256, 0, stream>>>(Aq8, Wo8, out, xs + 3 * R, wscale, 3, D);
}

// Round 7
// 465.139 us; speedup vs baseline: 1.2185x; 1.2185x over previous
//
#include <hip/hip_runtime.h>
#include <stdint.h>

// Problem constants (fixed by setup_inputs)
constexpr int B   = 2;
constexpr int T   = 2048;
constexpr int D   = 2048;
constexpr int H   = 32;
constexpr int KVH = 8;
constexpr int HD  = 64;          // head dim
constexpr int R   = B * T;       // 4096 rows
constexpr int OKV = KVH * HD;    // 512

using bf16x8 = __attribute__((ext_vector_type(8))) __bf16;
using f32x4  = __attribute__((ext_vector_type(4))) float;
using i32x4  = __attribute__((ext_vector_type(4))) int;

__device__ inline float fast_exp2(float x) {
#if __has_builtin(__builtin_amdgcn_exp2f)
    return __builtin_amdgcn_exp2f(x);    // v_exp_f32: computes 2^x
#else
    return exp2f(x);
#endif
}

__device__ inline uint16_t f2bf(float f) {
    uint32_t u = __float_as_uint(f);
    u += 0x7fff + ((u >> 16) & 1);   // RNE
    return (uint16_t)(u >> 16);
}

__device__ inline uint32_t pack_bf16(float a, float b) {
#if __has_builtin(__builtin_amdgcn_cvt_pk_bf16_f32)
    union { __attribute__((ext_vector_type(2))) __bf16 v; uint32_t u; } r;
    r.v = __builtin_amdgcn_cvt_pk_bf16_f32(a, b);
    return r.u;
#else
    return (uint32_t)f2bf(a) | ((uint32_t)f2bf(b) << 16);
#endif
}

// async global->LDS, 16B per lane; LDS dest = (wave-uniform) base + lane*16
__device__ inline void async16(const void* g, void* l) {
    __builtin_amdgcn_global_load_lds((const __attribute__((address_space(1))) unsigned int*)g,
                                     (__attribute__((address_space(3))) unsigned int*)l,
                                     16, 0, 0);
}

// ---------------- weight scales: mean(|w|), all 4 weights in one launch --------
__global__ void absmean4_kernel(const float* __restrict__ w0, const float* __restrict__ w1,
                                const float* __restrict__ w2, const float* __restrict__ w3,
                                double* __restrict__ sums) {
    __shared__ float red[256];
    const float* ws[4] = {w0, w1, w2, w3};
    const int ns[4] = {D * D, OKV * D, OKV * D, D * D};
    int wi = blockIdx.y;
    const float* w = ws[wi];
    int n = ns[wi];
    int tid = threadIdx.x;
    float s = 0.f;
    for (int i = blockIdx.x * 256 + tid; i < n; i += gridDim.x * 256)
        s += fabsf(w[i]);
    red[tid] = s;
    __syncthreads();
    for (int st = 128; st > 0; st >>= 1) {
        if (tid < st) red[tid] += red[tid + st];
        __syncthreads();
    }
    if (tid == 0) atomicAdd(&sums[wi], (double)red[0]);
}

// ---------------- ternary weight quantization, all 4 in one launch ----------------
__global__ void quantw4_kernel(const float* __restrict__ w0, const float* __restrict__ w1,
                               const float* __restrict__ w2, const float* __restrict__ w3,
                               int8_t* __restrict__ o0, int8_t* __restrict__ o1,
                               int8_t* __restrict__ o2, int8_t* __restrict__ o3,
                               const double* __restrict__ sums) {
    const float* ws[4] = {w0, w1, w2, w3};
    int8_t* os[4] = {o0, o1, o2, o3};
    const int ns[4] = {D * D, OKV * D, OKV * D, D * D};
    int wi = blockIdx.y;
    const float* w = ws[wi];
    int8_t* o = os[wi];
    int n = ns[wi];
    float wsc = fmaxf((float)(sums[wi] / (double)n), 1e-5f);
    for (int i = blockIdx.x * 256 + threadIdx.x; i < n; i += gridDim.x * 256) {
        float q = rintf(w[i] / wsc);
        q = fminf(fmaxf(q, -1.f), 1.f);
        o[i] = (int8_t)q;
    }
}

// ---------------- fused rmsnorm + absmax int8 quant for q,k,v ----------------
__global__ __launch_bounds__(256) void rmsq3_kernel(const float* __restrict__ X,
        const float* __restrict__ g0, const float* __restrict__ g1, const float* __restrict__ g2,
        int8_t* __restrict__ o0, int8_t* __restrict__ o1, int8_t* __restrict__ o2,
        float* __restrict__ s0, float* __restrict__ s1, float* __restrict__ s2) {
    __shared__ float red[256];
    int row = blockIdx.x, tid = threadIdx.x;
    const float* xr = X + (size_t)row * D;
    float xv[8];
    float ss = 0.f;
#pragma unroll
    for (int i = 0; i < 8; i++) { xv[i] = xr[tid + 256 * i]; ss += xv[i] * xv[i]; }
    red[tid] = ss;
    __syncthreads();
    for (int st = 128; st > 0; st >>= 1) {
        if (tid < st) red[tid] += red[tid + st];
        __syncthreads();
    }
    float rstd = 1.0f / sqrtf(red[0] / (float)D + 1e-6f);

    const float* gs[3] = {g0, g1, g2};
    int8_t* os[3] = {o0, o1, o2};
    float* sc[3] = {s0, s1, s2};
#pragma unroll
    for (int v = 0; v < 3; v++) {
        float xn[8];
        float amax = 0.f;
#pragma unroll
        for (int i = 0; i < 8; i++) {
            xn[i] = xv[i] * rstd * gs[v][tid + 256 * i];
            amax = fmaxf(amax, fabsf(xn[i]));
        }
        __syncthreads();
        red[tid] = amax;
        __syncthreads();
        for (int st = 128; st > 0; st >>= 1) {
            if (tid < st) red[tid] = fmaxf(red[tid], red[tid + st]);
            __syncthreads();
        }
        float xsv = fmaxf(red[0], 1e-5f);
        float q127 = 127.0f / xsv;
#pragma unroll
        for (int i = 0; i < 8; i++) {
            float q = rintf(xn[i] * q127);
            q = fminf(fmaxf(q, -128.f), 127.f);
            os[v][(size_t)row * D + tid + 256 * i] = (int8_t)q;
        }
        if (tid == 0) sc[v][row] = xsv;
    }
}

// ---------------- rmsnorm + quant (single, for o-proj input) ----------------
__global__ void rmsq_kernel(const float* __restrict__ X, const float* __restrict__ g,
                            int8_t* __restrict__ Xq, float* __restrict__ xs_out) {
    __shared__ float red[256];
    int row = blockIdx.x;
    int tid = threadIdx.x;
    const float* xr = X + (size_t)row * D;

    float ss = 0.f;
    for (int i = tid; i < D; i += 256) { float v = xr[i]; ss += v * v; }
    red[tid] = ss;
    __syncthreads();
    for (int st = 128; st > 0; st >>= 1) {
        if (tid < st) red[tid] += red[tid + st];
        __syncthreads();
    }
    float ms = red[0] / (float)D;
    float rstd = 1.0f / sqrtf(ms + 1e-6f);
    __syncthreads();

    float amax = 0.f;
    for (int i = tid; i < D; i += 256) {
        float xn = xr[i] * rstd * g[i];
        amax = fmaxf(amax, fabsf(xn));
    }
    red[tid] = amax;
    __syncthreads();
    for (int st = 128; st > 0; st >>= 1) {
        if (tid < st) red[tid] = fmaxf(red[tid], red[tid + st]);
        __syncthreads();
    }
    float xs = fmaxf(red[0], 1e-5f);

    for (int i = tid; i < D; i += 256) {
        float xn = xr[i] * rstd * g[i];
        float q = rintf(xn * 127.0f / xs);
        q = fminf(fmaxf(q, -128.f), 127.f);
        Xq[(size_t)row * D + i] = (int8_t)q;
    }
    if (tid == 0) xs_out[row] = xs;
}

// ---------------- i8 MFMA GEMM ----------------
template<int BN>
__global__ __launch_bounds__(256) void gemm_i8_mfma(const int8_t* __restrict__ Xq,
                                                    const int8_t* __restrict__ W8,
                                                    float* __restrict__ out,
                                                    const float* __restrict__ xs,
                                                    const double* __restrict__ wsum, int wi,
                                                    int nw, int O) {
    constexpr int NT = BN / 32;          // n-tiles per wave
    __shared__ __align__(16) uint8_t As[128 * 128];
    __shared__ __align__(16) uint8_t Bs[BN * 128];

    const int tid  = threadIdx.x;
    const int lane = tid & 63;
    const int wv   = tid >> 6;
    const int n    = lane & 15, quad = lane >> 4;
    const int row0 = blockIdx.y * 128;
    const int col0 = blockIdx.x * BN;
    const int ws_m = (wv >> 1) * 64;
    const int ws_n = (wv & 1) * (BN / 2);

    i32x4 acc[4][NT] = {};

    for (int k0 = 0; k0 < D; k0 += 128) {
        __syncthreads();
#pragma unroll
        for (int j = 0; j < 4; j++) {
            int p = wv * 256 + j * 64 + lane;
            int r = p >> 3, s = p & 7;
            int c = s ^ (r & 7);
            async16(Xq + (size_t)(row0 + r) * D + k0 + c * 16,
                    &As[(size_t)(wv * 256 + j * 64) * 16]);
        }
#pragma unroll
        for (int j = 0; j < NT; j++) {
            int p = wv * (BN * 2) + j * 64 + lane;
            int r = p >> 3, s = p & 7;
            int c = s ^ (r & 7);
            async16(W8 + (size_t)(col0 + r) * D + k0 + c * 16,
                    &Bs[(size_t)(wv * (BN * 2) + j * 64) * 16]);
        }
        __syncthreads();
#pragma unroll
        for (int t = 0; t < 2; t++) {
            i32x4 af[4], bfr[NT];
#pragma unroll
            for (int mt = 0; mt < 4; mt++) {
                int r = ws_m + mt * 16 + n;
                af[mt] = *(const i32x4*)&As[r * 128 + (((t * 4 + quad) ^ (r & 7)) * 16)];
            }
#pragma unroll
            for (int nt = 0; nt < NT; nt++) {
                int r = ws_n + nt * 16 + n;
                bfr[nt] = *(const i32x4*)&Bs[r * 128 + (((t * 4 + quad) ^ (r & 7)) * 16)];
            }
#pragma unroll
            for (int mt = 0; mt < 4; mt++)
#pragma unroll
                for (int nt = 0; nt < NT; nt++)
                    acc[mt][nt] = __builtin_amdgcn_mfma_i32_16x16x64_i8(af[mt], bfr[nt], acc[mt][nt], 0, 0, 0);
        }
    }
    float w = fmaxf((float)(wsum[wi] / (double)nw), 1e-5f);
#pragma unroll
    for (int mt = 0; mt < 4; mt++) {
#pragma unroll
        for (int r2 = 0; r2 < 4; r2++) {
            int row = row0 + ws_m + mt * 16 + quad * 4 + r2;
            float f = w * xs[row] * (1.0f / 127.0f);
#pragma unroll
            for (int nt = 0; nt < NT; nt++) {
                int col = col0 + ws_n + nt * 16 + n;
                out[(size_t)row * O + col] = (float)acc[mt][nt][r2] * f;
            }
        }
    }
}

// ---------------- RoPE fp32 -> bf16 ----------------
__global__ void rope_bf16_kernel(const float* __restrict__ x, const float* __restrict__ cs,
                                 const float* __restrict__ sn, uint16_t* __restrict__ o,
                                 int NH, int total) {
    int idx = blockIdx.x * 256 + threadIdx.x;
    if (idx >= total) return;
    int i = idx & 31;                 // 0..31
    int hh = (idx >> 5) % NH;
    int bt = idx / (32 * NH);         // b*T + t
    int t = bt % T;
    size_t base = ((size_t)bt * NH + hh) * HD;
    float x0 = x[base + i], x1 = x[base + i + 32];
    float c0 = cs[t * HD + i], c1 = cs[t * HD + i + 32];
    float s0 = sn[t * HD + i], s1 = sn[t * HD + i + 32];
    o[base + i]      = f2bf(x0 * c0 - x1 * s0);
    o[base + i + 32] = f2bf(x1 * c1 + x0 * s1);
}

// ---------------- V transpose: [t][kvh*64+d] f32 -> [b*KVH+kvh][d][t] bf16 --------
__global__ __launch_bounds__(256) void vtrans_kernel(const float* __restrict__ vb,
                                                     uint16_t* __restrict__ vt) {
    __shared__ float tile[64][65];
    int t0 = blockIdx.x * 64;
    int hb = blockIdx.y;              // b*KVH + kvh
    int b = hb >> 3, kvh = hb & 7;
    int tid = threadIdx.x;
    int r = tid >> 2, cg = (tid & 3) * 16;
#pragma unroll
    for (int j = 0; j < 4; j++) {
        float4 v4 = *(const float4*)(vb + (size_t)(b * T + t0 + r) * OKV + kvh * HD + cg + j * 4);
        tile[r][cg + j * 4 + 0] = v4.x;
        tile[r][cg + j * 4 + 1] = v4.y;
        tile[r][cg + j * 4 + 2] = v4.z;
        tile[r][cg + j * 4 + 3] = v4.w;
    }
    __syncthreads();
    int d = tid >> 2, tg = (tid & 3) * 16;
    uint16_t pk[16];
#pragma unroll
    for (int j = 0; j < 16; j++) pk[j] = f2bf(tile[tg + j][d]);
    *(uint4*)(vt + ((size_t)hb * 64 + d) * T + t0 + tg)     = *(uint4*)&pk[0];
    *(uint4*)(vt + ((size_t)hb * 64 + d) * T + t0 + tg + 8) = *(uint4*)&pk[8];
}

// ---------------- MFMA flash attention: dbuf LDS staging, strip-paired ----------
// grid (4, H, B) = 256 blocks (1/CU). Block p handles causal strips p and 7-p
// (256 q each); wave wv owns 8 q-tiles: strip*256 + wv*64 + qt*16.
// K [key][d] and V^T [d][key] double-buffered in LDS via swizzled
// global_load_lds, prefetch for chunk ch+1 issued BEFORE computing chunk ch so
// the vmcnt(0) drain at the barrier finds loads complete.
__global__ __launch_bounds__(256, 1) void attn_mfma_kernel(const uint16_t* __restrict__ qh,
                                                           const uint16_t* __restrict__ kh,
                                                           const uint16_t* __restrict__ vt,
                                                           float* __restrict__ out) {
    __shared__ __align__(16) uint16_t KsB[2][64 * 64];
    __shared__ __align__(16) uint16_t VtB[2][64 * 64];
    __shared__ __align__(16) uint16_t Pw[4][128 * 72];   // per-wave P [q][key]

    const int tid  = threadIdx.x;
    const int lane = tid & 63;
    const int wv   = tid >> 6;
    const int p = blockIdx.x, h = blockIdx.y, b = blockIdx.z;
    const int kvh = h >> 2;               // n_rep = 4
    const int n = lane & 15, quad = lane >> 4;
    const float SC = 0.125f * 1.44269504089f;   // score -> log2 units

    // 8 q-tiles: 0..3 strip p, 4..7 strip 7-p
    int q_lo[8];
#pragma unroll
    for (int i = 0; i < 8; i++)
        q_lo[i] = ((i < 4) ? p : (7 - p)) * 256 + wv * 64 + (i & 3) * 16;

    bf16x8 qf[8][2];
#pragma unroll
    for (int i = 0; i < 8; i++) {
        const uint16_t* qp = qh + (size_t)(b * T + q_lo[i] + n) * D + h * HD + quad * 8;
        qf[i][0] = *(const bf16x8*)(qp);
        qf[i][1] = *(const bf16x8*)(qp + 32);
    }

    f32x4 o[8][4] = {};
    float m[8], l[8];
#pragma unroll
    for (int i = 0; i < 8; i++) { m[i] = -INFINITY; l[i] = 0.f; }

    const uint16_t* kbase = kh + (size_t)b * T * OKV + kvh * HD;
    const uint16_t* vbase = vt + (size_t)(b * KVH + kvh) * 64 * T;

    const int nch = 4 * (8 - p);          // chunks for the longer strip (7-p)

    // stage chunk 0 -> buf 0
#pragma unroll
    for (int j = 0; j < 2; j++) {
        int pp = wv * 128 + j * 64 + lane;
        int r = pp >> 3, sl = pp & 7;
        int c = sl ^ (r & 7);
        async16(kbase + (size_t)r * OKV + c * 8, &KsB[0][(wv * 128 + j * 64) * 8]);
        async16(vbase + (size_t)r * T + c * 8,   &VtB[0][(wv * 128 + j * 64) * 8]);
    }
    __syncthreads();

    for (int ch = 0; ch < nch; ch++) {
        const int cur = ch & 1;
        // prefetch chunk ch+1 into alternate buffer (issued before compute)
        if (ch + 1 < nch) {
            const int t1 = (ch + 1) * 64;
#pragma unroll
            for (int j = 0; j < 2; j++) {
                int pp = wv * 128 + j * 64 + lane;
                int r = pp >> 3, sl = pp & 7;
                int c = sl ^ (r & 7);
                async16(kbase + (size_t)(t1 + r) * OKV + c * 8, &KsB[cur ^ 1][(wv * 128 + j * 64) * 8]);
                async16(vbase + (size_t)r * T + t1 + c * 8,     &VtB[cur ^ 1][(wv * 128 + j * 64) * 8]);
            }
        }
        const int t0 = ch * 64;

        // K / V^T fragments from current buffer
        bf16x8 kf[2][4], vf[2][4];
#pragma unroll
        for (int ks = 0; ks < 2; ks++)
#pragma unroll
            for (int mt = 0; mt < 4; mt++) {
                int r = mt * 16 + n;
                int cc = (((ks * 4 + quad) ^ (n & 7)) * 8);
                kf[ks][mt] = *(const bf16x8*)&KsB[cur][r * 64 + cc];
                vf[ks][mt] = *(const bf16x8*)&VtB[cur][r * 64 + cc];
            }

        // pass 1: QK^T + softmax + P -> per-wave LDS
#pragma unroll
        for (int i = 0; i < 8; i++) {
            if (t0 > q_lo[i] + 15) continue;
            f32x4 sv[4] = {};
#pragma unroll
            for (int ks = 0; ks < 2; ks++)
#pragma unroll
                for (int mt = 0; mt < 4; mt++)
                    sv[mt] = __builtin_amdgcn_mfma_f32_16x16x32_bf16(kf[ks][mt], qf[i][ks], sv[mt], 0, 0, 0);

            const int qg = q_lo[i] + n;
            const bool diag = (t0 + 63 > q_lo[i]);
            float mloc = -INFINITY;
#pragma unroll
            for (int mt = 0; mt < 4; mt++)
#pragma unroll
                for (int r2 = 0; r2 < 4; r2++) {
                    float x = sv[mt][r2];
                    if (diag) {
                        int kg = t0 + mt * 16 + quad * 4 + r2;
                        x = (kg > qg) ? -INFINITY : x;
                        sv[mt][r2] = x;
                    }
                    mloc = fmaxf(mloc, x);
                }
            mloc = fmaxf(mloc, __shfl_xor(mloc, 16));
            mloc = fmaxf(mloc, __shfl_xor(mloc, 32));
            float mnew = fmaxf(m[i], mloc);
            float msc = mnew * SC;
            float corr = fast_exp2(m[i] * SC - msc);
            float ls = 0.f;
#pragma unroll
            for (int mt = 0; mt < 4; mt++) {
                float pv[4];
#pragma unroll
                for (int r2 = 0; r2 < 4; r2++) {
                    pv[r2] = fast_exp2(__builtin_fmaf(sv[mt][r2], SC, -msc));
                    ls += pv[r2];
                }
                uint2 w2;
                w2.x = pack_bf16(pv[0], pv[1]);
                w2.y = pack_bf16(pv[2], pv[3]);
                *(uint2*)&Pw[wv][((i * 16 + n) * 72) + mt * 16 + quad * 4] = w2;
            }
            ls += __shfl_xor(ls, 16);
            ls += __shfl_xor(ls, 32);
            l[i] = l[i] * corr + ls;
            m[i] = mnew;
#pragma unroll
            for (int mt = 0; mt < 4; mt++)
#pragma unroll
                for (int r2 = 0; r2 < 4; r2++) o[i][mt][r2] *= corr;
        }

        // pass 2: O^T += V^T P^T
#pragma unroll
        for (int i = 0; i < 8; i++) {
            if (t0 > q_lo[i] + 15) continue;
#pragma unroll
            for (int ks = 0; ks < 2; ks++) {
                bf16x8 pf = *(const bf16x8*)&Pw[wv][((i * 16 + n) * 72) + ks * 32 + quad * 8];
#pragma unroll
                for (int mt = 0; mt < 4; mt++)
                    o[i][mt] = __builtin_amdgcn_mfma_f32_16x16x32_bf16(vf[ks][mt], pf, o[i][mt], 0, 0, 0);
            }
        }
        __syncthreads();   // publish next buffer; prefetch had full compute to land
    }

#pragma unroll
    for (int i = 0; i < 8; i++) {
        int qg = q_lo[i] + n;
        float inv = 1.0f / l[i];
#pragma unroll
        for (int mt = 0; mt < 4; mt++) {
            f32x4 ov;
#pragma unroll
            for (int r2 = 0; r2 < 4; r2++) ov[r2] = o[i][mt][r2] * inv;
            *(f32x4*)(out + (size_t)(b * T + qg) * D + h * HD + mt * 16 + quad * 4) = ov;
        }
    }
}

// ---------------- launch ----------------
extern "C" void kernel_launch(void* const* d_in, const int* in_sizes, int n_in,
                              void* d_out, int out_size, void* d_ws, size_t ws_size,
                              hipStream_t stream) {
    const float* x   = (const float*)d_in[0];
    const float* cs  = (const float*)d_in[1];
    const float* sn  = (const float*)d_in[2];
    const float* wq  = (const float*)d_in[3];
    const float* wk  = (const float*)d_in[4];
    const float* wv  = (const float*)d_in[5];
    const float* wo  = (const float*)d_in[6];
    const float* gq  = (const float*)d_in[7];
    const float* gk  = (const float*)d_in[8];
    const float* gv  = (const float*)d_in[9];
    const float* go  = (const float*)d_in[10];
    float* out = (float*)d_out;

    uint8_t* w = (uint8_t*)d_ws;
    double* wsum  = (double*)w;
    float* xs     = (float*)(w + 256);
    size_t off = 256 + 4 * (size_t)R * 4;
    int8_t* Wq8 = (int8_t*)(w + off); off += (size_t)D * D;
    int8_t* Wk8 = (int8_t*)(w + off); off += (size_t)OKV * D;
    int8_t* Wv8 = (int8_t*)(w + off); off += (size_t)OKV * D;
    int8_t* Wo8 = (int8_t*)(w + off); off += (size_t)D * D;
    int8_t* Xq_q = (int8_t*)(w + off); off += (size_t)R * D;
    int8_t* Xq_k = (int8_t*)(w + off); off += (size_t)R * D;
    int8_t* Xq_v = (int8_t*)(w + off); off += (size_t)R * D;
    float* qb = (float*)(w + off); off += (size_t)R * D * 4;
    float* kb = (float*)(w + off); off += (size_t)R * OKV * 4;
    float* vb = (float*)(w + off); off += (size_t)R * OKV * 4;
    uint16_t* qhb = (uint16_t*)(w + off); off += (size_t)R * D * 2;
    // overlays (regions dead by the time they're written):
    uint16_t* khb = (uint16_t*)Xq_v;   // dead after v gemm
    uint16_t* vtb = (uint16_t*)Xq_k;   // dead after k gemm; 4MB needed, 8MB region
    float*    ab  = qb;                // dead after rope q
    int8_t*   Aq8 = Xq_q;              // dead after q gemm (rewritten after attention)

    (void)hipMemsetAsync(wsum, 0, 64, stream);

    absmean4_kernel<<<dim3(256, 4), 256, 0, stream>>>(wq, wk, wv, wo, wsum);
    quantw4_kernel<<<dim3(1024, 4), 256, 0, stream>>>(wq, wk, wv, wo, Wq8, Wk8, Wv8, Wo8, wsum);

    rmsq3_kernel<<<R, 256, 0, stream>>>(x, gq, gk, gv, Xq_q, Xq_k, Xq_v,
                                        xs + 0 * R, xs + 1 * R, xs + 2 * R);

    gemm_i8_mfma<128><<<dim3(D / 128, R / 128), 256, 0, stream>>>(Xq_q, Wq8, qb, xs + 0 * R, wsum, 0, D * D, D);
    gemm_i8_mfma<64><<<dim3(OKV / 64, R / 128), 256, 0, stream>>>(Xq_k, Wk8, kb, xs + 1 * R, wsum, 1, OKV * D, OKV);
    gemm_i8_mfma<64><<<dim3(OKV / 64, R / 128), 256, 0, stream>>>(Xq_v, Wv8, vb, xs + 2 * R, wsum, 2, OKV * D, OKV);

    {
        int totq = R * H * 32;
        rope_bf16_kernel<<<(totq + 255) / 256, 256, 0, stream>>>(qb, cs, sn, qhb, H, totq);
        int totk = R * KVH * 32;
        rope_bf16_kernel<<<(totk + 255) / 256, 256, 0, stream>>>(kb, cs, sn, khb, KVH, totk);
        vtrans_kernel<<<dim3(T / 64, B * KVH), 256, 0, stream>>>(vb, vtb);
    }

    attn_mfma_kernel<<<dim3(4, H, B), 256, 0, stream>>>(qhb, khb, vtb, ab);

    rmsq_kernel<<<R, 256, 0, stream>>>(ab, go, Aq8, xs + 3 * R);
    gemm_i8_mfma<128><<<dim3(D / 128, R / 128), 256, 0, stream>>>(Aq8, Wo8, out, xs + 3 * R, wsum, 3, D * D, D);
}

// Round 8
// 407.874 us; speedup vs baseline: 1.3896x; 1.1404x over previous
//
#include <hip/hip_runtime.h>
#include <stdint.h>

// Problem constants (fixed by setup_inputs)
constexpr int B   = 2;
constexpr int T   = 2048;
constexpr int D   = 2048;
constexpr int H   = 32;
constexpr int KVH = 8;
constexpr int HD  = 64;          // head dim
constexpr int R   = B * T;       // 4096 rows
constexpr int OKV = KVH * HD;    // 512

using bf16x8 = __attribute__((ext_vector_type(8))) __bf16;
using f32x4  = __attribute__((ext_vector_type(4))) float;
using i32x4  = __attribute__((ext_vector_type(4))) int;

__device__ inline float fast_exp2(float x) {
#if __has_builtin(__builtin_amdgcn_exp2f)
    return __builtin_amdgcn_exp2f(x);    // v_exp_f32: computes 2^x
#else
    return exp2f(x);
#endif
}

__device__ inline uint16_t f2bf(float f) {
    uint32_t u = __float_as_uint(f);
    u += 0x7fff + ((u >> 16) & 1);   // RNE
    return (uint16_t)(u >> 16);
}

__device__ inline uint32_t pack_bf16(float a, float b) {
#if __has_builtin(__builtin_amdgcn_cvt_pk_bf16_f32)
    union { __attribute__((ext_vector_type(2))) __bf16 v; uint32_t u; } r;
    r.v = __builtin_amdgcn_cvt_pk_bf16_f32(a, b);
    return r.u;
#else
    return (uint32_t)f2bf(a) | ((uint32_t)f2bf(b) << 16);
#endif
}

// async global->LDS, 16B per lane; LDS dest = (wave-uniform) base + lane*16
__device__ inline void async16(const void* g, void* l) {
    __builtin_amdgcn_global_load_lds((const __attribute__((address_space(1))) unsigned int*)g,
                                     (__attribute__((address_space(3))) unsigned int*)l,
                                     16, 0, 0);
}

// ---------------- weight scales: mean(|w|), all 4 weights in one launch --------
__global__ void absmean4_kernel(const float* __restrict__ w0, const float* __restrict__ w1,
                                const float* __restrict__ w2, const float* __restrict__ w3,
                                double* __restrict__ sums) {
    __shared__ float red[256];
    const float* ws[4] = {w0, w1, w2, w3};
    const int ns[4] = {D * D, OKV * D, OKV * D, D * D};
    int wi = blockIdx.y;
    const float* w = ws[wi];
    int n = ns[wi];
    int tid = threadIdx.x;
    float s = 0.f;
    for (int i = blockIdx.x * 256 + tid; i < n; i += gridDim.x * 256)
        s += fabsf(w[i]);
    red[tid] = s;
    __syncthreads();
    for (int st = 128; st > 0; st >>= 1) {
        if (tid < st) red[tid] += red[tid + st];
        __syncthreads();
    }
    if (tid == 0) atomicAdd(&sums[wi], (double)red[0]);
}

// ---------------- ternary weight quantization, all 4 in one launch ----------------
__global__ void quantw4_kernel(const float* __restrict__ w0, const float* __restrict__ w1,
                               const float* __restrict__ w2, const float* __restrict__ w3,
                               int8_t* __restrict__ o0, int8_t* __restrict__ o1,
                               int8_t* __restrict__ o2, int8_t* __restrict__ o3,
                               const double* __restrict__ sums) {
    const float* ws[4] = {w0, w1, w2, w3};
    int8_t* os[4] = {o0, o1, o2, o3};
    const int ns[4] = {D * D, OKV * D, OKV * D, D * D};
    int wi = blockIdx.y;
    const float* w = ws[wi];
    int8_t* o = os[wi];
    int n = ns[wi];
    float wsc = fmaxf((float)(sums[wi] / (double)n), 1e-5f);
    for (int i = blockIdx.x * 256 + threadIdx.x; i < n; i += gridDim.x * 256) {
        float q = rintf(w[i] / wsc);
        q = fminf(fmaxf(q, -1.f), 1.f);
        o[i] = (int8_t)q;
    }
}

// ---------------- fused rmsnorm + absmax int8 quant for q,k,v ----------------
__global__ __launch_bounds__(256) void rmsq3_kernel(const float* __restrict__ X,
        const float* __restrict__ g0, const float* __restrict__ g1, const float* __restrict__ g2,
        int8_t* __restrict__ o0, int8_t* __restrict__ o1, int8_t* __restrict__ o2,
        float* __restrict__ s0, float* __restrict__ s1, float* __restrict__ s2) {
    __shared__ float red[256];
    int row = blockIdx.x, tid = threadIdx.x;
    const float* xr = X + (size_t)row * D;
    float xv[8];
    float ss = 0.f;
#pragma unroll
    for (int i = 0; i < 8; i++) { xv[i] = xr[tid + 256 * i]; ss += xv[i] * xv[i]; }
    red[tid] = ss;
    __syncthreads();
    for (int st = 128; st > 0; st >>= 1) {
        if (tid < st) red[tid] += red[tid + st];
        __syncthreads();
    }
    float rstd = 1.0f / sqrtf(red[0] / (float)D + 1e-6f);

    const float* gs[3] = {g0, g1, g2};
    int8_t* os[3] = {o0, o1, o2};
    float* sc[3] = {s0, s1, s2};
#pragma unroll
    for (int v = 0; v < 3; v++) {
        float xn[8];
        float amax = 0.f;
#pragma unroll
        for (int i = 0; i < 8; i++) {
            xn[i] = xv[i] * rstd * gs[v][tid + 256 * i];
            amax = fmaxf(amax, fabsf(xn[i]));
        }
        __syncthreads();
        red[tid] = amax;
        __syncthreads();
        for (int st = 128; st > 0; st >>= 1) {
            if (tid < st) red[tid] = fmaxf(red[tid], red[tid + st]);
            __syncthreads();
        }
        float xsv = fmaxf(red[0], 1e-5f);
        float q127 = 127.0f / xsv;
#pragma unroll
        for (int i = 0; i < 8; i++) {
            float q = rintf(xn[i] * q127);
            q = fminf(fmaxf(q, -128.f), 127.f);
            os[v][(size_t)row * D + tid + 256 * i] = (int8_t)q;
        }
        if (tid == 0) sc[v][row] = xsv;
    }
}

// ---------------- rmsnorm + quant (single, for o-proj input) ----------------
__global__ void rmsq_kernel(const float* __restrict__ X, const float* __restrict__ g,
                            int8_t* __restrict__ Xq, float* __restrict__ xs_out) {
    __shared__ float red[256];
    int row = blockIdx.x;
    int tid = threadIdx.x;
    const float* xr = X + (size_t)row * D;

    float ss = 0.f;
    for (int i = tid; i < D; i += 256) { float v = xr[i]; ss += v * v; }
    red[tid] = ss;
    __syncthreads();
    for (int st = 128; st > 0; st >>= 1) {
        if (tid < st) red[tid] += red[tid + st];
        __syncthreads();
    }
    float ms = red[0] / (float)D;
    float rstd = 1.0f / sqrtf(ms + 1e-6f);
    __syncthreads();

    float amax = 0.f;
    for (int i = tid; i < D; i += 256) {
        float xn = xr[i] * rstd * g[i];
        amax = fmaxf(amax, fabsf(xn));
    }
    red[tid] = amax;
    __syncthreads();
    for (int st = 128; st > 0; st >>= 1) {
        if (tid < st) red[tid] = fmaxf(red[tid], red[tid + st]);
        __syncthreads();
    }
    float xs = fmaxf(red[0], 1e-5f);

    for (int i = tid; i < D; i += 256) {
        float xn = xr[i] * rstd * g[i];
        float q = rintf(xn * 127.0f / xs);
        q = fminf(fmaxf(q, -128.f), 127.f);
        Xq[(size_t)row * D + i] = (int8_t)q;
    }
    if (tid == 0) xs_out[row] = xs;
}

// ---------------- i8 MFMA GEMM ----------------
template<int BN>
__global__ __launch_bounds__(256) void gemm_i8_mfma(const int8_t* __restrict__ Xq,
                                                    const int8_t* __restrict__ W8,
                                                    float* __restrict__ out,
                                                    const float* __restrict__ xs,
                                                    const double* __restrict__ wsum, int wi,
                                                    int nw, int O) {
    constexpr int NT = BN / 32;          // n-tiles per wave
    __shared__ __align__(16) uint8_t As[128 * 128];
    __shared__ __align__(16) uint8_t Bs[BN * 128];

    const int tid  = threadIdx.x;
    const int lane = tid & 63;
    const int wv   = tid >> 6;
    const int n    = lane & 15, quad = lane >> 4;
    const int row0 = blockIdx.y * 128;
    const int col0 = blockIdx.x * BN;
    const int ws_m = (wv >> 1) * 64;
    const int ws_n = (wv & 1) * (BN / 2);

    i32x4 acc[4][NT] = {};

    for (int k0 = 0; k0 < D; k0 += 128) {
        __syncthreads();
#pragma unroll
        for (int j = 0; j < 4; j++) {
            int p = wv * 256 + j * 64 + lane;
            int r = p >> 3, s = p & 7;
            int c = s ^ (r & 7);
            async16(Xq + (size_t)(row0 + r) * D + k0 + c * 16,
                    &As[(size_t)(wv * 256 + j * 64) * 16]);
        }
#pragma unroll
        for (int j = 0; j < NT; j++) {
            int p = wv * (BN * 2) + j * 64 + lane;
            int r = p >> 3, s = p & 7;
            int c = s ^ (r & 7);
            async16(W8 + (size_t)(col0 + r) * D + k0 + c * 16,
                    &Bs[(size_t)(wv * (BN * 2) + j * 64) * 16]);
        }
        __syncthreads();
#pragma unroll
        for (int t = 0; t < 2; t++) {
            i32x4 af[4], bfr[NT];
#pragma unroll
            for (int mt = 0; mt < 4; mt++) {
                int r = ws_m + mt * 16 + n;
                af[mt] = *(const i32x4*)&As[r * 128 + (((t * 4 + quad) ^ (r & 7)) * 16)];
            }
#pragma unroll
            for (int nt = 0; nt < NT; nt++) {
                int r = ws_n + nt * 16 + n;
                bfr[nt] = *(const i32x4*)&Bs[r * 128 + (((t * 4 + quad) ^ (r & 7)) * 16)];
            }
#pragma unroll
            for (int mt = 0; mt < 4; mt++)
#pragma unroll
                for (int nt = 0; nt < NT; nt++)
                    acc[mt][nt] = __builtin_amdgcn_mfma_i32_16x16x64_i8(af[mt], bfr[nt], acc[mt][nt], 0, 0, 0);
        }
    }
    float w = fmaxf((float)(wsum[wi] / (double)nw), 1e-5f);
#pragma unroll
    for (int mt = 0; mt < 4; mt++) {
#pragma unroll
        for (int r2 = 0; r2 < 4; r2++) {
            int row = row0 + ws_m + mt * 16 + quad * 4 + r2;
            float f = w * xs[row] * (1.0f / 127.0f);
#pragma unroll
            for (int nt = 0; nt < NT; nt++) {
                int col = col0 + ws_n + nt * 16 + n;
                out[(size_t)row * O + col] = (float)acc[mt][nt][r2] * f;
            }
        }
    }
}

// ---------------- RoPE fp32 -> bf16 ----------------
__global__ void rope_bf16_kernel(const float* __restrict__ x, const float* __restrict__ cs,
                                 const float* __restrict__ sn, uint16_t* __restrict__ o,
                                 int NH, int total) {
    int idx = blockIdx.x * 256 + threadIdx.x;
    if (idx >= total) return;
    int i = idx & 31;                 // 0..31
    int hh = (idx >> 5) % NH;
    int bt = idx / (32 * NH);         // b*T + t
    int t = bt % T;
    size_t base = ((size_t)bt * NH + hh) * HD;
    float x0 = x[base + i], x1 = x[base + i + 32];
    float c0 = cs[t * HD + i], c1 = cs[t * HD + i + 32];
    float s0 = sn[t * HD + i], s1 = sn[t * HD + i + 32];
    o[base + i]      = f2bf(x0 * c0 - x1 * s0);
    o[base + i + 32] = f2bf(x1 * c1 + x0 * s1);
}

// ---------------- V transpose: [t][kvh*64+d] f32 -> [b*KVH+kvh][d][t] bf16 --------
__global__ __launch_bounds__(256) void vtrans_kernel(const float* __restrict__ vb,
                                                     uint16_t* __restrict__ vt) {
    __shared__ float tile[64][65];
    int t0 = blockIdx.x * 64;
    int hb = blockIdx.y;              // b*KVH + kvh
    int b = hb >> 3, kvh = hb & 7;
    int tid = threadIdx.x;
    int r = tid >> 2, cg = (tid & 3) * 16;
#pragma unroll
    for (int j = 0; j < 4; j++) {
        float4 v4 = *(const float4*)(vb + (size_t)(b * T + t0 + r) * OKV + kvh * HD + cg + j * 4);
        tile[r][cg + j * 4 + 0] = v4.x;
        tile[r][cg + j * 4 + 1] = v4.y;
        tile[r][cg + j * 4 + 2] = v4.z;
        tile[r][cg + j * 4 + 3] = v4.w;
    }
    __syncthreads();
    int d = tid >> 2, tg = (tid & 3) * 16;
    uint16_t pk[16];
#pragma unroll
    for (int j = 0; j < 16; j++) pk[j] = f2bf(tile[tg + j][d]);
    *(uint4*)(vt + ((size_t)hb * 64 + d) * T + t0 + tg)     = *(uint4*)&pk[0];
    *(uint4*)(vt + ((size_t)hb * 64 + d) * T + t0 + tg + 8) = *(uint4*)&pk[8];
}

// ---------------- MFMA flash attention: 2 blocks/CU, dbuf staging ----------
// grid (8, H, B) = 512 blocks (2/CU, 2 waves/SIMD). Block p handles causal
// strips p and 15-p (128 q each); wave wv owns 4 q-tiles:
// strip*128 + wv*32 + {0,16}. l accumulated via ones-row MFMA (no shfl tree).
__global__ __launch_bounds__(256, 2) void attn_mfma_kernel(const uint16_t* __restrict__ qh,
                                                           const uint16_t* __restrict__ kh,
                                                           const uint16_t* __restrict__ vt,
                                                           float* __restrict__ out) {
    __shared__ __align__(16) uint16_t KsB[2][64 * 64];
    __shared__ __align__(16) uint16_t VtB[2][64 * 64];
    __shared__ __align__(16) uint16_t Pw[4][16 * 72];   // per-wave P [q][key] (one tile)

    const int tid  = threadIdx.x;
    const int lane = tid & 63;
    const int wv   = tid >> 6;
    const int p = blockIdx.x, h = blockIdx.y, b = blockIdx.z;
    const int kvh = h >> 2;               // n_rep = 4
    const int n = lane & 15, quad = lane >> 4;
    const float SC = 0.125f * 1.44269504089f;   // score -> log2 units

    // ones A-frag for l-accumulation MFMA
    union { bf16x8 v; uint16_t u[8]; } onesf;
#pragma unroll
    for (int j = 0; j < 8; j++) onesf.u[j] = 0x3F80;   // bf16 1.0

    // 4 q-tiles: 0..1 strip p, 2..3 strip 15-p
    int q_lo[4];
#pragma unroll
    for (int i = 0; i < 4; i++)
        q_lo[i] = ((i < 2) ? p : (15 - p)) * 128 + wv * 32 + (i & 1) * 16;

    bf16x8 qf[4][2];
#pragma unroll
    for (int i = 0; i < 4; i++) {
        const uint16_t* qp = qh + (size_t)(b * T + q_lo[i] + n) * D + h * HD + quad * 8;
        qf[i][0] = *(const bf16x8*)(qp);
        qf[i][1] = *(const bf16x8*)(qp + 32);
    }

    f32x4 o[4][4] = {};
    f32x4 lacc[4] = {};
    float m[4];
#pragma unroll
    for (int i = 0; i < 4; i++) m[i] = -INFINITY;

    const uint16_t* kbase = kh + (size_t)b * T * OKV + kvh * HD;
    const uint16_t* vbase = vt + (size_t)(b * KVH + kvh) * 64 * T;

    const int nch = 32 - 2 * p;           // chunks for the longer strip (15-p)

    // stage chunk 0 -> buf 0
#pragma unroll
    for (int j = 0; j < 2; j++) {
        int pp = wv * 128 + j * 64 + lane;
        int r = pp >> 3, sl = pp & 7;
        int c = sl ^ (r & 7);
        async16(kbase + (size_t)r * OKV + c * 8, &KsB[0][(wv * 128 + j * 64) * 8]);
        async16(vbase + (size_t)r * T + c * 8,   &VtB[0][(wv * 128 + j * 64) * 8]);
    }
    __syncthreads();

    for (int ch = 0; ch < nch; ch++) {
        const int cur = ch & 1;
        if (ch + 1 < nch) {   // prefetch next chunk into alternate buffer
            const int t1 = (ch + 1) * 64;
#pragma unroll
            for (int j = 0; j < 2; j++) {
                int pp = wv * 128 + j * 64 + lane;
                int r = pp >> 3, sl = pp & 7;
                int c = sl ^ (r & 7);
                async16(kbase + (size_t)(t1 + r) * OKV + c * 8, &KsB[cur ^ 1][(wv * 128 + j * 64) * 8]);
                async16(vbase + (size_t)r * T + t1 + c * 8,     &VtB[cur ^ 1][(wv * 128 + j * 64) * 8]);
            }
        }
        const int t0 = ch * 64;

        // K / V^T fragments from current buffer
        bf16x8 kf[2][4], vf[2][4];
#pragma unroll
        for (int ks = 0; ks < 2; ks++)
#pragma unroll
            for (int mt = 0; mt < 4; mt++) {
                int r = mt * 16 + n;
                int cc = (((ks * 4 + quad) ^ (n & 7)) * 8);
                kf[ks][mt] = *(const bf16x8*)&KsB[cur][r * 64 + cc];
                vf[ks][mt] = *(const bf16x8*)&VtB[cur][r * 64 + cc];
            }

        // fused per-tile: QK^T -> softmax -> P roundtrip -> PV^T (+ l via ones-MFMA)
#pragma unroll
        for (int i = 0; i < 4; i++) {
            if (t0 > q_lo[i] + 15) continue;
            f32x4 sv[4] = {};
#pragma unroll
            for (int ks = 0; ks < 2; ks++)
#pragma unroll
                for (int mt = 0; mt < 4; mt++)
                    sv[mt] = __builtin_amdgcn_mfma_f32_16x16x32_bf16(kf[ks][mt], qf[i][ks], sv[mt], 0, 0, 0);

            const int qg = q_lo[i] + n;
            const bool diag = (t0 + 63 > q_lo[i]);
            float mloc = -INFINITY;
#pragma unroll
            for (int mt = 0; mt < 4; mt++)
#pragma unroll
                for (int r2 = 0; r2 < 4; r2++) {
                    float x = sv[mt][r2];
                    if (diag) {
                        int kg = t0 + mt * 16 + quad * 4 + r2;
                        x = (kg > qg) ? -INFINITY : x;
                        sv[mt][r2] = x;
                    }
                    mloc = fmaxf(mloc, x);
                }
            mloc = fmaxf(mloc, __shfl_xor(mloc, 16));
            mloc = fmaxf(mloc, __shfl_xor(mloc, 32));
            bool upd = (mloc > m[i]);
            if (__ballot(upd)) {
                float mnew = fmaxf(m[i], mloc);
                float corr = upd ? fast_exp2((m[i] - mnew) * SC) : 1.0f;  // first chunk: 2^-inf=0
                m[i] = mnew;
#pragma unroll
                for (int mt = 0; mt < 4; mt++)
#pragma unroll
                    for (int r2 = 0; r2 < 4; r2++) o[i][mt][r2] *= corr;
                lacc[i][0] *= corr;
            }
            float msc = m[i] * SC;
#pragma unroll
            for (int mt = 0; mt < 4; mt++) {
                float pv[4];
#pragma unroll
                for (int r2 = 0; r2 < 4; r2++)
                    pv[r2] = fast_exp2(__builtin_fmaf(sv[mt][r2], SC, -msc));
                uint2 w2;
                w2.x = pack_bf16(pv[0], pv[1]);
                w2.y = pack_bf16(pv[2], pv[3]);
                *(uint2*)&Pw[wv][n * 72 + mt * 16 + quad * 4] = w2;
            }
#pragma unroll
            for (int ks = 0; ks < 2; ks++) {
                bf16x8 pf = *(const bf16x8*)&Pw[wv][n * 72 + ks * 32 + quad * 8];
#pragma unroll
                for (int mt = 0; mt < 4; mt++)
                    o[i][mt] = __builtin_amdgcn_mfma_f32_16x16x32_bf16(vf[ks][mt], pf, o[i][mt], 0, 0, 0);
                lacc[i] = __builtin_amdgcn_mfma_f32_16x16x32_bf16(onesf.v, pf, lacc[i], 0, 0, 0);
            }
        }
        __syncthreads();   // publish next buffer (prefetch had full compute to land)
    }

#pragma unroll
    for (int i = 0; i < 4; i++) {
        int qg = q_lo[i] + n;
        float inv = 1.0f / lacc[i][0];
#pragma unroll
        for (int mt = 0; mt < 4; mt++) {
            f32x4 ov;
#pragma unroll
            for (int r2 = 0; r2 < 4; r2++) ov[r2] = o[i][mt][r2] * inv;
            *(f32x4*)(out + (size_t)(b * T + qg) * D + h * HD + mt * 16 + quad * 4) = ov;
        }
    }
}

// ---------------- launch ----------------
extern "C" void kernel_launch(void* const* d_in, const int* in_sizes, int n_in,
                              void* d_out, int out_size, void* d_ws, size_t ws_size,
                              hipStream_t stream) {
    const float* x   = (const float*)d_in[0];
    const float* cs  = (const float*)d_in[1];
    const float* sn  = (const float*)d_in[2];
    const float* wq  = (const float*)d_in[3];
    const float* wk  = (const float*)d_in[4];
    const float* wv  = (const float*)d_in[5];
    const float* wo  = (const float*)d_in[6];
    const float* gq  = (const float*)d_in[7];
    const float* gk  = (const float*)d_in[8];
    const float* gv  = (const float*)d_in[9];
    const float* go  = (const float*)d_in[10];
    float* out = (float*)d_out;

    uint8_t* w = (uint8_t*)d_ws;
    double* wsum  = (double*)w;
    float* xs     = (float*)(w + 256);
    size_t off = 256 + 4 * (size_t)R * 4;
    int8_t* Wq8 = (int8_t*)(w + off); off += (size_t)D * D;
    int8_t* Wk8 = (int8_t*)(w + off); off += (size_t)OKV * D;
    int8_t* Wv8 = (int8_t*)(w + off); off += (size_t)OKV * D;
    int8_t* Wo8 = (int8_t*)(w + off); off += (size_t)D * D;
    int8_t* Xq_q = (int8_t*)(w + off); off += (size_t)R * D;
    int8_t* Xq_k = (int8_t*)(w + off); off += (size_t)R * D;
    int8_t* Xq_v = (int8_t*)(w + off); off += (size_t)R * D;
    float* qb = (float*)(w + off); off += (size_t)R * D * 4;
    float* kb = (float*)(w + off); off += (size_t)R * OKV * 4;
    float* vb = (float*)(w + off); off += (size_t)R * OKV * 4;
    uint16_t* qhb = (uint16_t*)(w + off); off += (size_t)R * D * 2;
    // overlays (regions dead by the time they're written):
    uint16_t* khb = (uint16_t*)Xq_v;   // dead after v gemm
    uint16_t* vtb = (uint16_t*)Xq_k;   // dead after k gemm; 4MB needed, 8MB region
    float*    ab  = qb;                // dead after rope q
    int8_t*   Aq8 = Xq_q;              // dead after q gemm (rewritten after attention)

    (void)hipMemsetAsync(wsum, 0, 64, stream);

    absmean4_kernel<<<dim3(256, 4), 256, 0, stream>>>(wq, wk, wv, wo, wsum);
    quantw4_kernel<<<dim3(1024, 4), 256, 0, stream>>>(wq, wk, wv, wo, Wq8, Wk8, Wv8, Wo8, wsum);

    rmsq3_kernel<<<R, 256, 0, stream>>>(x, gq, gk, gv, Xq_q, Xq_k, Xq_v,
                                        xs + 0 * R, xs + 1 * R, xs + 2 * R);

    gemm_i8_mfma<128><<<dim3(D / 128, R / 128), 256, 0, stream>>>(Xq_q, Wq8, qb, xs + 0 * R, wsum, 0, D * D, D);
    gemm_i8_mfma<64><<<dim3(OKV / 64, R / 128), 256, 0, stream>>>(Xq_k, Wk8, kb, xs + 1 * R, wsum, 1, OKV * D, OKV);
    gemm_i8_mfma<64><<<dim3(OKV / 64, R / 128), 256, 0, stream>>>(Xq_v, Wv8, vb, xs + 2 * R, wsum, 2, OKV * D, OKV);

    {
        int totq = R * H * 32;
        rope_bf16_kernel<<<(totq + 255) / 256, 256, 0, stream>>>(qb, cs, sn, qhb, H, totq);
        int totk = R * KVH * 32;
        rope_bf16_kernel<<<(totk + 255) / 256, 256, 0, stream>>>(kb, cs, sn, khb, KVH, totk);
        vtrans_kernel<<<dim3(T / 64, B * KVH), 256, 0, stream>>>(vb, vtb);
    }

    attn_mfma_kernel<<<dim3(8, H, B), 256, 0, stream>>>(qhb, khb, vtb, ab);

    rmsq_kernel<<<R, 256, 0, stream>>>(ab, go, Aq8, xs + 3 * R);
    gemm_i8_mfma<128><<<dim3(D / 128, R / 128), 256, 0, stream>>>(Aq8, Wo8, out, xs + 3 * R, wsum, 3, D * D, D);
}